// Round 10
// baseline (431.003 us; speedup 1.0000x reference)
//
#include <hip/hip_runtime.h>
#include <math.h>

#define NEG_SLOPE 0.2f

typedef __attribute__((ext_vector_type(8))) short bf16x8;
typedef __attribute__((ext_vector_type(4))) float f32x4;

__device__ __forceinline__ float leaky(float v){ return v > 0.f ? v : NEG_SLOPE * v; }

// round-to-nearest-even f32 -> bf16 bits
static __device__ __forceinline__ unsigned int f2bf(float x){
  unsigned u = __float_as_uint(x);
  return (u + 0x7fffu + ((u >> 16) & 1u)) >> 16;
}

// ---------------- fused prep (no grid barrier, independent chains as block ranges) -----
// b==0        : wst (logit weights) -> set wflag
// b in [1,33) : packh (W1 -> MFMA B-fragments)
// b >= 33     : striped 2:1 -> {hist + edge-rank} | {logits + xb tiles (spin on wflag)}
__global__ __launch_bounds__(256) void k_prep(
    const float* __restrict__ W1, const float* __restrict__ as, const float* __restrict__ ad,
    float* __restrict__ wst, bf16x8* __restrict__ packh,
    const int* __restrict__ dstp, int* __restrict__ deg, int* __restrict__ erk,
    const float* __restrict__ x, float* __restrict__ s, float* __restrict__ t,
    unsigned int* __restrict__ xb, int* __restrict__ wflag,
    int N, int E, int nhist, int ntiles)
{
  __shared__ float xs[32][133];          // 133 = 5 mod 32: conflict-free node stride
  __shared__ float wl[2048];
  int tid = threadIdx.x;
  int b = blockIdx.x;

  if (b == 0){
    // wst[k*16 + o]: o<8 -> W1.a_src head o ; o>=8 -> W1.a_dst head o-8
    for (int idx = tid; idx < 2048; idx += 256){
      int k = idx >> 4, o = idx & 15, half = o >> 3, hh = o & 7;
      const float* a = half ? ad : as;
      const float* wrow = W1 + (size_t)k * 512 + hh * 64;
      float sum = 0.f;
      for (int c = 0; c < 64; ++c) sum += wrow[c] * a[hh * 64 + c];
      wst[idx] = sum;
    }
    __threadfence();
    __syncthreads();
    if (tid == 0) __hip_atomic_store(wflag, 1, __ATOMIC_RELEASE, __HIP_MEMORY_SCOPE_AGENT);
  } else if (b < 33){
    int g = (b - 1) * 256 + tid;         // 0..8191
    int gl = g & 63, kt = (g >> 6) & 3, ctl = (g >> 8) & 3, hh = g >> 10;
    int gc = hh * 64 + ctl * 16 + (gl & 15);
    int k0 = kt * 32 + (gl >> 4) * 8;
    bf16x8 hv;
    #pragma unroll
    for (int i = 0; i < 8; ++i)
      hv[i] = (short)f2bf(W1[(size_t)(k0 + i) * 512 + gc]);
    packh[g] = hv;
  } else {
    int rem = b - 33;
    int q = rem / 3, r3 = rem - q * 3;
    if (r3 < 2){
      // ---------------- hist + rank ----------------
      int hb = q * 2 + r3;
      if (hb < nhist){
        int i = hb * 256 + tid;
        if (i < E){
          int d = dstp[i];
          erk[i] = atomicAdd(&deg[d], 1);
        }
      }
    } else {
      // ---------------- logits + xb tile (32 nodes) ----------------
      int tb = q;
      if (tb < ntiles){
        if (tid == 0){
          while (__hip_atomic_load(wflag, __ATOMIC_ACQUIRE, __HIP_MEMORY_SCOPE_AGENT) == 0)
            __builtin_amdgcn_s_sleep(2);
        }
        __syncthreads();
        for (int i = tid; i < 2048; i += 256) wl[i] = wst[i];
        int n0 = tb * 32;
        for (int i = tid; i < 1024; i += 256){
          int r = i >> 5, c4 = (i & 31) << 2;
          float4 v = make_float4(0.f, 0.f, 0.f, 0.f);
          if (n0 + r < N) v = *(const float4*)(x + (size_t)(n0 + r) * 128 + c4);
          xs[r][c4 + 0] = v.x; xs[r][c4 + 1] = v.y; xs[r][c4 + 2] = v.z; xs[r][c4 + 3] = v.w;
        }
        __syncthreads();
        int node = tid & 31, og = tid >> 5;     // 2 outputs per thread
        float a0 = 0.f, a1 = 0.f;
        for (int k = 0; k < 128; ++k){
          float v = xs[node][k];
          float2 w2 = *(const float2*)&wl[k * 16 + og * 2];
          a0 += v * w2.x;
          a1 += v * w2.y;
        }
        int n = n0 + node;
        if (n < N){
          int o = og * 2;
          if (o < 8){ s[n * 8 + o] = a0; s[n * 8 + o + 1] = a1; }
          else      { t[n * 8 + o - 8] = a0; t[n * 8 + o - 7] = a1; }
        }
        for (int i = tid; i < 2048; i += 256){
          int r = i >> 6, j = i & 63;
          int n2 = n0 + r;
          if (n2 < N)
            xb[(size_t)n2 * 64 + j] = f2bf(xs[r][2 * j]) | (f2bf(xs[r][2 * j + 1]) << 16);
        }
      }
    }
  }
}

// ---------------- scan1: per-256-block inclusive scan of deg ----------------
__global__ void k_scan1(const int* __restrict__ deg, int* __restrict__ tmp,
                        int* __restrict__ bsum, int N){
  __shared__ int ws[4];
  int tid = threadIdx.x;
  int i = blockIdx.x * 256 + tid;
  int v = (i < N) ? deg[i] : 0;
  int lane = tid & 63, wv = tid >> 6;
  int x = v;
  #pragma unroll
  for (int off = 1; off < 64; off <<= 1){
    int y = __shfl_up(x, off, 64);
    if (lane >= off) x += y;
  }
  if (lane == 63) ws[wv] = x;
  __syncthreads();
  int p = 0;
  for (int w = 0; w < wv; ++w) p += ws[w];
  x += p;
  if (i < N) tmp[i] = x;
  if (tid == 255) bsum[blockIdx.x] = x;
}

// ---------------- fill3: local bsum scan + rowptr + atomic-free CSR scatter ------------
__global__ __launch_bounds__(256) void k_fill3(const int* __restrict__ src,
                        const int* __restrict__ dst, int E,
                        const int* __restrict__ tmp, const int* __restrict__ bsumraw,
                        const int* __restrict__ erk,
                        int* __restrict__ rowptr, int* __restrict__ esrc, int N, int nb){
  __shared__ int bs[256];
  __shared__ int ws[4];
  int tid = threadIdx.x;
  {
    int v = (tid < nb) ? bsumraw[tid] : 0;
    int lane = tid & 63, wv = tid >> 6;
    int x = v;
    #pragma unroll
    for (int off = 1; off < 64; off <<= 1){
      int y = __shfl_up(x, off, 64);
      if (lane >= off) x += y;
    }
    if (lane == 63) ws[wv] = x;
    __syncthreads();
    int p = 0;
    for (int w = 0; w < wv; ++w) p += ws[w];
    bs[tid] = x + p;
    __syncthreads();
  }
  int i = blockIdx.x * 256 + tid;
  if (i <= N){
    int r;
    if (i == 0) r = 0;
    else { int ii = i - 1, blk = ii >> 8; r = tmp[ii] + (blk ? bs[blk - 1] : 0); }
    rowptr[i] = r;
  }
  if (i < E){
    int d = dst[i];
    int ii = d - 1, blk = ii >> 8;
    int row0 = (d == 0) ? 0 : tmp[ii] + (blk ? bs[blk - 1] : 0);
    esrc[row0 + erk[i]] = src[i];     // rank precomputed in hist: no atomics here
  }
}

// ---------------- fused aggregation + MFMA projection (R8-proven body) ----------------
__global__ __launch_bounds__(512, 8) void k_agg_gemm(
    const unsigned int* __restrict__ xb,   // [N][64] uint = [N][128] bf16
    const float* __restrict__ s, const float* __restrict__ t,
    const int* __restrict__ rowptr, const int* __restrict__ esrc,
    const bf16x8* __restrict__ packh,
    const float* __restrict__ b1, const float* __restrict__ W2,
    float* __restrict__ xh2, int N)
{
  __shared__ unsigned int ylds[8192];      // 16 nodes x 1024 bf16 = 32 KB
  __shared__ float lal[8][128];
  __shared__ float red[8][16];
  int tid = threadIdx.x;
  int w = tid >> 6, lane = tid & 63;
  int m0 = blockIdx.x * 16;
  int h = lane & 7;
  int es = lane >> 3;

  // ---------------- phase 1: aggregation (2 nodes per wave) ----------------
  for (int ni = 0; ni < 2; ++ni){
    int nl = w * 2 + ni;                   // local node 0..15
    int n = m0 + nl;
    float acc[16];
    #pragma unroll
    for (int i = 0; i < 16; ++i) acc[i] = 0.f;

    if (n < N){
      int row0 = rowptr[n], deg = rowptr[n + 1] - row0;
      float tn = t[(size_t)n * 8 + h];
      float sn = s[(size_t)n * 8 + h];
      float selfe = __expf(leaky(sn + tn));

      // self message (un-normalized)
      {
        unsigned int v = xb[(size_t)n * 64 + lane];
        float f0 = __uint_as_float(v << 16);
        float f1 = __uint_as_float(v & 0xffff0000u);
        #pragma unroll
        for (int hh = 0; hh < 8; ++hh){
          float a = __shfl(selfe, hh, 64);
          acc[2 * hh]     += a * f0;
          acc[2 * hh + 1] += a * f1;
        }
      }
      float dsum = (lane < 8) ? selfe : 0.f;

      float* lb = lal[w];
      for (int base = 0; base < deg; base += 8){
        float* la = lb + ((base >> 3) & 1) * 64;   // double-buffer
        int e = base + es;
        int cnt = min(8, deg - base);
        int srcl = 0;
        if (e < deg) srcl = esrc[row0 + e];
        float sv = s[(size_t)srcl * 8 + h];        // gather (srcl=0 safe for OOB)
        // broadcast src ids, issue all 8 x-gathers up-front (MLP=8)
        int sj[8];
        #pragma unroll
        for (int j = 0; j < 8; ++j) sj[j] = __shfl(srcl, j << 3, 64);
        unsigned int vv[8];
        #pragma unroll
        for (int j = 0; j < 8; ++j) vv[j] = xb[(size_t)sj[j] * 64 + lane];
        float ev = (e < deg) ? __expf(leaky(sv + tn)) : 0.f;
        dsum += ev;
        la[lane] = ev;
        #pragma unroll
        for (int j = 0; j < 8; ++j){
          if (j < cnt){
            float4 q0 = *(float4*)&la[j * 8];
            float4 q1 = *(float4*)&la[j * 8 + 4];
            float f0 = __uint_as_float(vv[j] << 16);
            float f1 = __uint_as_float(vv[j] & 0xffff0000u);
            acc[0]  += q0.x * f0; acc[1]  += q0.x * f1;
            acc[2]  += q0.y * f0; acc[3]  += q0.y * f1;
            acc[4]  += q0.z * f0; acc[5]  += q0.z * f1;
            acc[6]  += q0.w * f0; acc[7]  += q0.w * f1;
            acc[8]  += q1.x * f0; acc[9]  += q1.x * f1;
            acc[10] += q1.y * f0; acc[11] += q1.y * f1;
            acc[12] += q1.z * f0; acc[13] += q1.z * f1;
            acc[14] += q1.w * f0; acc[15] += q1.w * f1;
          }
        }
      }

      // finalize: per-head denominators, normalize
      dsum += __shfl_xor(dsum, 8, 64);
      dsum += __shfl_xor(dsum, 16, 64);
      dsum += __shfl_xor(dsum, 32, 64);
      float iden = 1.f / dsum;
      #pragma unroll
      for (int hh = 0; hh < 8; ++hh){
        float a = __shfl(iden, hh, 64);
        acc[2 * hh]     *= a;
        acc[2 * hh + 1] *= a;
      }
    }

    // write y tile to LDS (swizzled); zeros for n >= N
    #pragma unroll
    for (int hh = 0; hh < 8; ++hh){
      unsigned int p = f2bf(acc[2 * hh]) | (f2bf(acc[2 * hh + 1]) << 16);
      unsigned int byte = (unsigned)(nl * 2048 + hh * 256 + lane * 4);
      byte ^= (unsigned)((nl & 7) << 4);
      ylds[byte >> 2] = p;
    }
  }
  __syncthreads();

  // ---------------- phase 2: MFMA projection (head = wave id) + fused epilogue ----------
  int lr = lane & 15, lg = lane >> 4;
  int hD = w;
  float pnode[4] = {0.f, 0.f, 0.f, 0.f};
  bf16x8 A[4];
  #pragma unroll
  for (int kt = 0; kt < 4; ++kt){
    unsigned int byte = (unsigned)(lr * 2048 + hD * 256 + kt * 64 + lg * 16);
    byte ^= (unsigned)((lr & 7) << 4);
    A[kt] = *(const bf16x8*)((const char*)ylds + byte);
  }
  #pragma unroll
  for (int ctl = 0; ctl < 4; ++ctl){
    f32x4 acc2 = {0.f, 0.f, 0.f, 0.f};
    int pb = ((hD * 4 + ctl) * 4) * 64 + lane;
    #pragma unroll
    for (int kt = 0; kt < 4; ++kt)
      acc2 = __builtin_amdgcn_mfma_f32_16x16x32_bf16(A[kt], packh[pb + kt * 64], acc2, 0, 0, 0);
    int gc = hD * 64 + ctl * 16 + lr;
    float bb = b1[gc], wvv = W2[gc];
    #pragma unroll
    for (int r = 0; r < 4; ++r){
      float o = acc2[r] + bb; o = o > 0.f ? o : 0.f;
      pnode[r] += o * wvv;                 // node = m0 + lg*4 + r
    }
  }
  #pragma unroll
  for (int r = 0; r < 4; ++r){
    float v = pnode[r];
    v += __shfl_xor(v, 1, 64);
    v += __shfl_xor(v, 2, 64);
    v += __shfl_xor(v, 4, 64);
    v += __shfl_xor(v, 8, 64);
    pnode[r] = v;
  }
  if (lr == 0){
    #pragma unroll
    for (int r = 0; r < 4; ++r) red[w][lg * 4 + r] = pnode[r];
  }
  __syncthreads();
  if (tid < 16){
    int node = m0 + tid;
    if (node < N){
      float sum = 0.f;
      #pragma unroll
      for (int ww = 0; ww < 8; ++ww) sum += red[ww][tid];
      xh2[node] = sum;
    }
  }
}

// ---------------- agg2: scalar GAT layer (H=1,C=1), 8 lanes per node --------------------
__global__ __launch_bounds__(256) void k_agg2(const float* __restrict__ xh2,
                       const int* __restrict__ rowptr, const int* __restrict__ esrc,
                       const float* __restrict__ as2p, const float* __restrict__ ad2p,
                       const float* __restrict__ b2p,
                       float* __restrict__ out, int N)
{
  int g = blockIdx.x * 32 + (threadIdx.x >> 3);
  int li = threadIdx.x & 7;
  if (g >= N) return;
  float a_s = as2p[0], a_d = ad2p[0], b2 = b2p[0];
  float xn = xh2[g];
  float t2 = a_d * xn;
  float den = 0.f, num = 0.f;
  if (li == 0){
    float w0 = __expf(leaky(a_s * xn + t2));   // self loop
    den = w0; num = w0 * xn;
  }
  int row1 = rowptr[g + 1];
  for (int e = rowptr[g] + li; e < row1; e += 8){
    int src = esrc[e];
    float xs2 = xh2[src];
    float w = __expf(leaky(a_s * xs2 + t2));
    den += w; num += w * xs2;
  }
  den += __shfl_xor(den, 1, 64); num += __shfl_xor(num, 1, 64);
  den += __shfl_xor(den, 2, 64); num += __shfl_xor(num, 2, 64);
  den += __shfl_xor(den, 4, 64); num += __shfl_xor(num, 4, 64);
  if (li == 0) out[g] = num / den + b2;
}

extern "C" void kernel_launch(void* const* d_in, const int* in_sizes, int n_in,
                              void* d_out, int out_size, void* d_ws, size_t ws_size,
                              hipStream_t stream) {
  const float* x   = (const float*)d_in[0];
  const int*   ei  = (const int*)d_in[1];
  const float* W1  = (const float*)d_in[2];
  const float* as1 = (const float*)d_in[3];
  const float* ad1 = (const float*)d_in[4];
  const float* b1  = (const float*)d_in[5];
  const float* W2  = (const float*)d_in[6];
  const float* as2 = (const float*)d_in[7];
  const float* ad2 = (const float*)d_in[8];
  const float* b2  = (const float*)d_in[9];
  float* out = (float*)d_out;

  int N = in_sizes[0] / 128;
  int E = in_sizes[1] / 2;
  const int* src_in = ei;
  const int* dst_in = ei + E;

  char* w = (char*)d_ws;
  auto alloc = [&](size_t bytes){ void* p = (void*)w; w += (bytes + 255) & ~(size_t)255; return p; };
  unsigned int* xb   = (unsigned int*)alloc((size_t)N * 64 * 4);    // 12.8 MB
  float* s      = (float*)alloc((size_t)N * 8 * 4);
  float* t      = (float*)alloc((size_t)N * 8 * 4);
  float* xh2    = (float*)alloc((size_t)N * 4);
  int*   cnts   = (int*)alloc((size_t)(N + 64) * 4);                // deg | wflag
  int*   deg    = cnts;
  int*   wflag  = cnts + N;
  int*   rowptr = (int*)alloc((size_t)(N + 1) * 4);
  int*   esrc   = (int*)alloc((size_t)E * 4);
  int*   erk    = (int*)alloc((size_t)E * 4);
  int*   tmp    = (int*)alloc((size_t)N * 4);
  int*   bsum   = (int*)alloc((size_t)1024 * 4);
  float* wst    = (float*)alloc((size_t)2048 * 4);
  bf16x8* packh = (bf16x8*)alloc((size_t)8192 * 16);

  int nb     = (N + 255) / 256;
  int nhist  = (E + 255) / 256;
  int ntiles = (N + 31) / 32;
  int ng3    = (nhist + 1) / 2; if (ntiles > ng3) ng3 = ntiles;

  hipMemsetAsync(cnts, 0, (size_t)(N + 64) * 4, stream);
  k_prep<<<33 + 3 * ng3, 256, 0, stream>>>(W1, as1, ad1, wst, packh, dst_in, deg, erk,
                                           x, s, t, xb, wflag, N, E, nhist, ntiles);
  k_scan1<<<nb, 256, 0, stream>>>(deg, tmp, bsum, N);
  k_fill3<<<(E + 255) / 256, 256, 0, stream>>>(src_in, dst_in, E, tmp, bsum, erk,
                                               rowptr, esrc, N, nb);
  k_agg_gemm<<<(N + 15) / 16, 512, 0, stream>>>(xb, s, t, rowptr, esrc, packh, b1, W2, xh2, N);
  k_agg2<<<(N + 31) / 32, 256, 0, stream>>>(xh2, rowptr, esrc, as2, ad2, b2, out, N);
}

// Round 11
// 170.381 us; speedup vs baseline: 2.5296x; 2.5296x over previous
//
#include <hip/hip_runtime.h>
#include <math.h>

#define NEG_SLOPE 0.2f

typedef __attribute__((ext_vector_type(8))) short bf16x8;
typedef __attribute__((ext_vector_type(4))) float f32x4;

__device__ __forceinline__ float leaky(float v){ return v > 0.f ? v : NEG_SLOPE * v; }

// round-to-nearest-even f32 -> bf16 bits
static __device__ __forceinline__ unsigned int f2bf(float x){
  unsigned u = __float_as_uint(x);
  return (u + 0x7fffu + ((u >> 16) & 1u)) >> 16;
}

// ---------------- prep0: wst (b==0) | packh (b in [1,33)) | sharded hist+rank (b>=33) ---
// hist shard = b & 7: blocks round-robin over the 8 XCDs, so each shard's deg lines
// stay XCD-local in L2 (no cross-XCD atomic line ping-pong). erk[i] = rank in shard.
__global__ __launch_bounds__(256) void k_prep0(
    const float* __restrict__ W1, const float* __restrict__ as, const float* __restrict__ ad,
    float* __restrict__ wst, bf16x8* __restrict__ packh,
    const int* __restrict__ dstp, int* __restrict__ deg8, int* __restrict__ erk,
    int N, int E)
{
  int b = blockIdx.x, tid = threadIdx.x;
  if (b == 0){
    // wst[k*16+o]: o<8 -> (W1.a_src)[head o]; o>=8 -> (W1.a_dst)[head o-8]
    for (int idx = tid; idx < 2048; idx += 256){
      int k = idx >> 4, o = idx & 15, half = o >> 3, hh = o & 7;
      const float* a = half ? ad : as;
      const float* wrow = W1 + (size_t)k * 512 + hh * 64;
      float sum = 0.f;
      for (int c = 0; c < 64; ++c) sum += wrow[c] * a[hh * 64 + c];
      wst[idx] = sum;
    }
  } else if (b < 33){
    int g = (b - 1) * 256 + tid;         // 0..8191
    int gl = g & 63, kt = (g >> 6) & 3, ctl = (g >> 8) & 3, hh = g >> 10;
    int gc = hh * 64 + ctl * 16 + (gl & 15);
    int k0 = kt * 32 + (gl >> 4) * 8;
    bf16x8 hv;
    #pragma unroll
    for (int i = 0; i < 8; ++i)
      hv[i] = (short)f2bf(W1[(size_t)(k0 + i) * 512 + gc]);
    packh[g] = hv;
  } else {
    int i = (b - 33) * 256 + tid;
    if (i < E){
      int d = dstp[i];
      int s = b & 7;
      erk[i] = atomicAdd(&deg8[(size_t)s * N + d], 1);
    }
  }
}

// ---------------- scan1: shard-sum + per-shard bases + per-256-chunk inclusive scan ----
__global__ void k_scan1(const int* __restrict__ deg8, int* __restrict__ sbase,
                        int* __restrict__ tmp, int* __restrict__ bsum, int N){
  __shared__ int ws[4];
  int tid = threadIdx.x;
  int i = blockIdx.x * 256 + tid;
  int total = 0;
  if (i < N){
    int run = 0;
    #pragma unroll
    for (int s = 0; s < 8; ++s){
      sbase[(size_t)s * N + i] = run;
      run += deg8[(size_t)s * N + i];
    }
    total = run;
  }
  int lane = tid & 63, wv = tid >> 6;
  int x = total;
  #pragma unroll
  for (int off = 1; off < 64; off <<= 1){
    int y = __shfl_up(x, off, 64);
    if (lane >= off) x += y;
  }
  if (lane == 63) ws[wv] = x;
  __syncthreads();
  int p = 0;
  for (int w = 0; w < wv; ++w) p += ws[w];
  x += p;
  if (i < N) tmp[i] = x;
  if (tid == 255) bsum[blockIdx.x] = x;
}

// ---------------- fill3: local bsum scan + rowptr + fully atomic-free CSR scatter ------
__global__ __launch_bounds__(256) void k_fill3(const int* __restrict__ src,
                        const int* __restrict__ dst, int E,
                        const int* __restrict__ tmp, const int* __restrict__ bsumraw,
                        const int* __restrict__ erk, const int* __restrict__ sbase,
                        int* __restrict__ rowptr, int* __restrict__ esrc, int N, int nb){
  __shared__ int bs[256];
  __shared__ int ws[4];
  int tid = threadIdx.x;
  {
    int v = (tid < nb) ? bsumraw[tid] : 0;
    int lane = tid & 63, wv = tid >> 6;
    int x = v;
    #pragma unroll
    for (int off = 1; off < 64; off <<= 1){
      int y = __shfl_up(x, off, 64);
      if (lane >= off) x += y;
    }
    if (lane == 63) ws[wv] = x;
    __syncthreads();
    int p = 0;
    for (int w = 0; w < wv; ++w) p += ws[w];
    bs[tid] = x + p;
    __syncthreads();
  }
  int i = blockIdx.x * 256 + tid;
  if (i <= N){
    int r;
    if (i == 0) r = 0;
    else { int ii = i - 1, blk = ii >> 8; r = tmp[ii] + (blk ? bs[blk - 1] : 0); }
    rowptr[i] = r;
  }
  if (i < E){
    int d = dst[i];
    int ii = d - 1, blk = ii >> 8;
    int row0 = (d == 0) ? 0 : tmp[ii] + (blk ? bs[blk - 1] : 0);
    int s = (33 + (i >> 8)) & 7;                 // same shard id hist used
    esrc[row0 + sbase[(size_t)s * N + d] + erk[i]] = src[i];
  }
}

// ---------------- logits (fp32 exact) + xb = bf16(x) ----------------
__global__ __launch_bounds__(256) void k_logits_xb(const float* __restrict__ x,
                                                   const float* __restrict__ wst,
                                                   float* __restrict__ s, float* __restrict__ t,
                                                   unsigned int* __restrict__ xb, int N){
  __shared__ float xs[64][133];          // 133 = 5 mod 32: conflict-free node stride
  __shared__ float wl[2048];
  int tid = threadIdx.x;
  int n0 = blockIdx.x * 64;
  for (int i = tid; i < 2048; i += 256) wl[i] = wst[i];
  for (int i = tid; i < 2048; i += 256){
    int r = i >> 5, c4 = (i & 31) << 2;
    float4 v = make_float4(0.f, 0.f, 0.f, 0.f);
    if (n0 + r < N) v = *(const float4*)(x + (size_t)(n0 + r) * 128 + c4);
    xs[r][c4 + 0] = v.x; xs[r][c4 + 1] = v.y; xs[r][c4 + 2] = v.z; xs[r][c4 + 3] = v.w;
  }
  __syncthreads();
  int node = tid & 63, og = tid >> 6;
  int o = og * 4;
  float a0 = 0.f, a1 = 0.f, a2 = 0.f, a3 = 0.f;
  for (int k = 0; k < 128; ++k){
    float v = xs[node][k];
    float4 wv4 = *(const float4*)&wl[k * 16 + o];   // wave-uniform broadcast read
    a0 += v * wv4.x;
    a1 += v * wv4.y;
    a2 += v * wv4.z;
    a3 += v * wv4.w;
  }
  int n = n0 + node;
  if (n < N){
    if (o < 8){
      s[n * 8 + o + 0] = a0; s[n * 8 + o + 1] = a1;
      s[n * 8 + o + 2] = a2; s[n * 8 + o + 3] = a3;
    } else {
      int oo = o - 8;
      t[n * 8 + oo + 0] = a0; t[n * 8 + oo + 1] = a1;
      t[n * 8 + oo + 2] = a2; t[n * 8 + oo + 3] = a3;
    }
  }
  for (int i = tid; i < 4096; i += 256){
    int r = i >> 6, j = i & 63;
    int n2 = n0 + r;
    if (n2 < N)
      xb[(size_t)n2 * 64 + j] = f2bf(xs[r][2 * j]) | (f2bf(xs[r][2 * j + 1]) << 16);
  }
}

// ---------------- fused aggregation + MFMA projection (R8-proven body, verbatim) -------
__global__ __launch_bounds__(512, 8) void k_agg_gemm(
    const unsigned int* __restrict__ xb,   // [N][64] uint = [N][128] bf16
    const float* __restrict__ s, const float* __restrict__ t,
    const int* __restrict__ rowptr, const int* __restrict__ esrc,
    const bf16x8* __restrict__ packh,
    const float* __restrict__ b1, const float* __restrict__ W2,
    float* __restrict__ xh2, int N)
{
  __shared__ unsigned int ylds[8192];      // 16 nodes x 1024 bf16 = 32 KB
  __shared__ float lal[8][128];
  __shared__ float red[8][16];
  int tid = threadIdx.x;
  int w = tid >> 6, lane = tid & 63;
  int m0 = blockIdx.x * 16;
  int h = lane & 7;
  int es = lane >> 3;

  // ---------------- phase 1: aggregation (2 nodes per wave) ----------------
  for (int ni = 0; ni < 2; ++ni){
    int nl = w * 2 + ni;                   // local node 0..15
    int n = m0 + nl;
    float acc[16];
    #pragma unroll
    for (int i = 0; i < 16; ++i) acc[i] = 0.f;

    if (n < N){
      int row0 = rowptr[n], deg = rowptr[n + 1] - row0;
      float tn = t[(size_t)n * 8 + h];
      float sn = s[(size_t)n * 8 + h];
      float selfe = __expf(leaky(sn + tn));

      // self message (un-normalized)
      {
        unsigned int v = xb[(size_t)n * 64 + lane];
        float f0 = __uint_as_float(v << 16);
        float f1 = __uint_as_float(v & 0xffff0000u);
        #pragma unroll
        for (int hh = 0; hh < 8; ++hh){
          float a = __shfl(selfe, hh, 64);
          acc[2 * hh]     += a * f0;
          acc[2 * hh + 1] += a * f1;
        }
      }
      float dsum = (lane < 8) ? selfe : 0.f;

      float* lb = lal[w];
      for (int base = 0; base < deg; base += 8){
        float* la = lb + ((base >> 3) & 1) * 64;   // double-buffer
        int e = base + es;
        int cnt = min(8, deg - base);
        int srcl = 0;
        if (e < deg) srcl = esrc[row0 + e];
        float sv = s[(size_t)srcl * 8 + h];        // gather (srcl=0 safe for OOB)
        // broadcast src ids, issue all 8 x-gathers up-front (MLP=8)
        int sj[8];
        #pragma unroll
        for (int j = 0; j < 8; ++j) sj[j] = __shfl(srcl, j << 3, 64);
        unsigned int vv[8];
        #pragma unroll
        for (int j = 0; j < 8; ++j) vv[j] = xb[(size_t)sj[j] * 64 + lane];
        float ev = (e < deg) ? __expf(leaky(sv + tn)) : 0.f;
        dsum += ev;
        la[lane] = ev;
        #pragma unroll
        for (int j = 0; j < 8; ++j){
          if (j < cnt){
            float4 q0 = *(float4*)&la[j * 8];
            float4 q1 = *(float4*)&la[j * 8 + 4];
            float f0 = __uint_as_float(vv[j] << 16);
            float f1 = __uint_as_float(vv[j] & 0xffff0000u);
            acc[0]  += q0.x * f0; acc[1]  += q0.x * f1;
            acc[2]  += q0.y * f0; acc[3]  += q0.y * f1;
            acc[4]  += q0.z * f0; acc[5]  += q0.z * f1;
            acc[6]  += q0.w * f0; acc[7]  += q0.w * f1;
            acc[8]  += q1.x * f0; acc[9]  += q1.x * f1;
            acc[10] += q1.y * f0; acc[11] += q1.y * f1;
            acc[12] += q1.z * f0; acc[13] += q1.z * f1;
            acc[14] += q1.w * f0; acc[15] += q1.w * f1;
          }
        }
      }

      // finalize: per-head denominators, normalize
      dsum += __shfl_xor(dsum, 8, 64);
      dsum += __shfl_xor(dsum, 16, 64);
      dsum += __shfl_xor(dsum, 32, 64);
      float iden = 1.f / dsum;
      #pragma unroll
      for (int hh = 0; hh < 8; ++hh){
        float a = __shfl(iden, hh, 64);
        acc[2 * hh]     *= a;
        acc[2 * hh + 1] *= a;
      }
    }

    // write y tile to LDS (swizzled); zeros for n >= N
    #pragma unroll
    for (int hh = 0; hh < 8; ++hh){
      unsigned int p = f2bf(acc[2 * hh]) | (f2bf(acc[2 * hh + 1]) << 16);
      unsigned int byte = (unsigned)(nl * 2048 + hh * 256 + lane * 4);
      byte ^= (unsigned)((nl & 7) << 4);
      ylds[byte >> 2] = p;
    }
  }
  __syncthreads();

  // ---------------- phase 2: MFMA projection (head = wave id) + fused epilogue ----------
  int lr = lane & 15, lg = lane >> 4;
  int hD = w;
  float pnode[4] = {0.f, 0.f, 0.f, 0.f};
  bf16x8 A[4];
  #pragma unroll
  for (int kt = 0; kt < 4; ++kt){
    unsigned int byte = (unsigned)(lr * 2048 + hD * 256 + kt * 64 + lg * 16);
    byte ^= (unsigned)((lr & 7) << 4);
    A[kt] = *(const bf16x8*)((const char*)ylds + byte);
  }
  #pragma unroll
  for (int ctl = 0; ctl < 4; ++ctl){
    f32x4 acc2 = {0.f, 0.f, 0.f, 0.f};
    int pb = ((hD * 4 + ctl) * 4) * 64 + lane;
    #pragma unroll
    for (int kt = 0; kt < 4; ++kt)
      acc2 = __builtin_amdgcn_mfma_f32_16x16x32_bf16(A[kt], packh[pb + kt * 64], acc2, 0, 0, 0);
    int gc = hD * 64 + ctl * 16 + lr;
    float bb = b1[gc], wvv = W2[gc];
    #pragma unroll
    for (int r = 0; r < 4; ++r){
      float o = acc2[r] + bb; o = o > 0.f ? o : 0.f;
      pnode[r] += o * wvv;                 // node = m0 + lg*4 + r
    }
  }
  #pragma unroll
  for (int r = 0; r < 4; ++r){
    float v = pnode[r];
    v += __shfl_xor(v, 1, 64);
    v += __shfl_xor(v, 2, 64);
    v += __shfl_xor(v, 4, 64);
    v += __shfl_xor(v, 8, 64);
    pnode[r] = v;
  }
  if (lr == 0){
    #pragma unroll
    for (int r = 0; r < 4; ++r) red[w][lg * 4 + r] = pnode[r];
  }
  __syncthreads();
  if (tid < 16){
    int node = m0 + tid;
    if (node < N){
      float sum = 0.f;
      #pragma unroll
      for (int ww = 0; ww < 8; ++ww) sum += red[ww][tid];
      xh2[node] = sum;
    }
  }
}

// ---------------- agg2: scalar GAT layer (H=1,C=1), 8 lanes per node --------------------
__global__ __launch_bounds__(256) void k_agg2(const float* __restrict__ xh2,
                       const int* __restrict__ rowptr, const int* __restrict__ esrc,
                       const float* __restrict__ as2p, const float* __restrict__ ad2p,
                       const float* __restrict__ b2p,
                       float* __restrict__ out, int N)
{
  int g = blockIdx.x * 32 + (threadIdx.x >> 3);
  int li = threadIdx.x & 7;
  if (g >= N) return;
  float a_s = as2p[0], a_d = ad2p[0], b2 = b2p[0];
  float xn = xh2[g];
  float t2 = a_d * xn;
  float den = 0.f, num = 0.f;
  if (li == 0){
    float w0 = __expf(leaky(a_s * xn + t2));   // self loop
    den = w0; num = w0 * xn;
  }
  int row1 = rowptr[g + 1];
  for (int e = rowptr[g] + li; e < row1; e += 8){
    int src = esrc[e];
    float xs2 = xh2[src];
    float w = __expf(leaky(a_s * xs2 + t2));
    den += w; num += w * xs2;
  }
  den += __shfl_xor(den, 1, 64); num += __shfl_xor(num, 1, 64);
  den += __shfl_xor(den, 2, 64); num += __shfl_xor(num, 2, 64);
  den += __shfl_xor(den, 4, 64); num += __shfl_xor(num, 4, 64);
  if (li == 0) out[g] = num / den + b2;
}

extern "C" void kernel_launch(void* const* d_in, const int* in_sizes, int n_in,
                              void* d_out, int out_size, void* d_ws, size_t ws_size,
                              hipStream_t stream) {
  const float* x   = (const float*)d_in[0];
  const int*   ei  = (const int*)d_in[1];
  const float* W1  = (const float*)d_in[2];
  const float* as1 = (const float*)d_in[3];
  const float* ad1 = (const float*)d_in[4];
  const float* b1  = (const float*)d_in[5];
  const float* W2  = (const float*)d_in[6];
  const float* as2 = (const float*)d_in[7];
  const float* ad2 = (const float*)d_in[8];
  const float* b2  = (const float*)d_in[9];
  float* out = (float*)d_out;

  int N = in_sizes[0] / 128;
  int E = in_sizes[1] / 2;
  const int* src_in = ei;
  const int* dst_in = ei + E;

  char* w = (char*)d_ws;
  auto alloc = [&](size_t bytes){ void* p = (void*)w; w += (bytes + 255) & ~(size_t)255; return p; };
  unsigned int* xb   = (unsigned int*)alloc((size_t)N * 64 * 4);    // 12.8 MB
  float* s      = (float*)alloc((size_t)N * 8 * 4);
  float* t      = (float*)alloc((size_t)N * 8 * 4);
  float* xh2    = (float*)alloc((size_t)N * 4);
  int*   deg8   = (int*)alloc((size_t)8 * N * 4);                   // sharded counters
  int*   sbase  = (int*)alloc((size_t)8 * N * 4);
  int*   rowptr = (int*)alloc((size_t)(N + 1) * 4);
  int*   esrc   = (int*)alloc((size_t)E * 4);
  int*   erk    = (int*)alloc((size_t)E * 4);
  int*   tmp    = (int*)alloc((size_t)N * 4);
  int*   bsum   = (int*)alloc((size_t)1024 * 4);
  float* wst    = (float*)alloc((size_t)2048 * 4);
  bf16x8* packh = (bf16x8*)alloc((size_t)8192 * 16);

  int nb    = (N + 255) / 256;
  int nhist = (E + 255) / 256;

  hipMemsetAsync(deg8, 0, (size_t)8 * N * 4, stream);
  k_prep0<<<33 + nhist, 256, 0, stream>>>(W1, as1, ad1, wst, packh, dst_in, deg8, erk, N, E);
  k_scan1<<<nb, 256, 0, stream>>>(deg8, sbase, tmp, bsum, N);
  k_fill3<<<(E + 255) / 256, 256, 0, stream>>>(src_in, dst_in, E, tmp, bsum, erk, sbase,
                                               rowptr, esrc, N, nb);
  k_logits_xb<<<(N + 63) / 64, 256, 0, stream>>>(x, wst, s, t, xb, N);
  k_agg_gemm<<<(N + 15) / 16, 512, 0, stream>>>(xb, s, t, rowptr, esrc, packh, b1, W2, xh2, N);
  k_agg2<<<(N + 31) / 32, 256, 0, stream>>>(xh2, rowptr, esrc, as2, ad2, b2, out, N);
}

// Round 12
// 169.350 us; speedup vs baseline: 2.5450x; 1.0061x over previous
//
#include <hip/hip_runtime.h>
#include <math.h>

#define NEG_SLOPE 0.2f

typedef __attribute__((ext_vector_type(8))) short bf16x8;
typedef __attribute__((ext_vector_type(4))) float f32x4;

__device__ __forceinline__ float leaky(float v){ return v > 0.f ? v : NEG_SLOPE * v; }

// round-to-nearest-even f32 -> bf16 bits
static __device__ __forceinline__ unsigned int f2bf(float x){
  unsigned u = __float_as_uint(x);
  return (u + 0x7fffu + ((u >> 16) & 1u)) >> 16;
}

// ---------------- prep0: wst (b==0) | packh (b in [1,33)) | sharded hist+rank (b>=33) ---
// hist shard = b & 7: blocks round-robin over the 8 XCDs, so each shard's deg lines
// stay XCD-local in L2 (no cross-XCD atomic line ping-pong). erk[i] = rank in shard.
__global__ __launch_bounds__(256) void k_prep0(
    const float* __restrict__ W1, const float* __restrict__ as, const float* __restrict__ ad,
    float* __restrict__ wst, bf16x8* __restrict__ packh,
    const int* __restrict__ dstp, int* __restrict__ deg8, int* __restrict__ erk,
    int N, int E)
{
  int b = blockIdx.x, tid = threadIdx.x;
  if (b == 0){
    // wst[k*16+o]: o<8 -> (W1.a_src)[head o]; o>=8 -> (W1.a_dst)[head o-8]
    for (int idx = tid; idx < 2048; idx += 256){
      int k = idx >> 4, o = idx & 15, half = o >> 3, hh = o & 7;
      const float* a = half ? ad : as;
      const float* wrow = W1 + (size_t)k * 512 + hh * 64;
      float sum = 0.f;
      for (int c = 0; c < 64; ++c) sum += wrow[c] * a[hh * 64 + c];
      wst[idx] = sum;
    }
  } else if (b < 33){
    int g = (b - 1) * 256 + tid;         // 0..8191
    int gl = g & 63, kt = (g >> 6) & 3, ctl = (g >> 8) & 3, hh = g >> 10;
    int gc = hh * 64 + ctl * 16 + (gl & 15);
    int k0 = kt * 32 + (gl >> 4) * 8;
    bf16x8 hv;
    #pragma unroll
    for (int i = 0; i < 8; ++i)
      hv[i] = (short)f2bf(W1[(size_t)(k0 + i) * 512 + gc]);
    packh[g] = hv;
  } else {
    int i = (b - 33) * 256 + tid;
    if (i < E){
      int d = dstp[i];
      int s = b & 7;
      erk[i] = atomicAdd(&deg8[(size_t)s * N + d], 1);
    }
  }
}

// ---------------- scanlog: scan1 (blocks [0,nb)) | logits+xb (blocks [nb, nb+ntiles)) --
// Independent chains merged as disjoint block ranges (both depend only on prep0).
__global__ __launch_bounds__(256) void k_scanlog(
    const int* __restrict__ deg8, int* __restrict__ sbase,
    int* __restrict__ tmp, int* __restrict__ bsum,
    const float* __restrict__ x, const float* __restrict__ wst,
    float* __restrict__ s, float* __restrict__ t, unsigned int* __restrict__ xb,
    int N, int nb)
{
  __shared__ float xs[64][133];          // 133 = 5 mod 32: conflict-free node stride
  __shared__ float wl[2048];
  __shared__ int ws4[4];
  int tid = threadIdx.x;
  int b = blockIdx.x;

  if (b < nb){
    // ---------------- scan1: shard-sum + per-shard bases + per-chunk inclusive scan ----
    int i = b * 256 + tid;
    int total = 0;
    if (i < N){
      int run = 0;
      #pragma unroll
      for (int sh = 0; sh < 8; ++sh){
        sbase[(size_t)sh * N + i] = run;
        run += deg8[(size_t)sh * N + i];
      }
      total = run;
    }
    int lane = tid & 63, wv = tid >> 6;
    int xv = total;
    #pragma unroll
    for (int off = 1; off < 64; off <<= 1){
      int y = __shfl_up(xv, off, 64);
      if (lane >= off) xv += y;
    }
    if (lane == 63) ws4[wv] = xv;
    __syncthreads();
    int p = 0;
    for (int w = 0; w < wv; ++w) p += ws4[w];
    xv += p;
    if (i < N) tmp[i] = xv;
    if (tid == 255) bsum[b] = xv;
  } else {
    // ---------------- logits (fp32 exact) + xb = bf16(x), 64-node tile ----------------
    int n0 = (b - nb) * 64;
    for (int i = tid; i < 2048; i += 256) wl[i] = wst[i];
    for (int i = tid; i < 2048; i += 256){
      int r = i >> 5, c4 = (i & 31) << 2;
      float4 v = make_float4(0.f, 0.f, 0.f, 0.f);
      if (n0 + r < N) v = *(const float4*)(x + (size_t)(n0 + r) * 128 + c4);
      xs[r][c4 + 0] = v.x; xs[r][c4 + 1] = v.y; xs[r][c4 + 2] = v.z; xs[r][c4 + 3] = v.w;
    }
    __syncthreads();
    int node = tid & 63, og = tid >> 6;
    int o = og * 4;
    float a0 = 0.f, a1 = 0.f, a2 = 0.f, a3 = 0.f;
    for (int k = 0; k < 128; ++k){
      float v = xs[node][k];
      float4 wv4 = *(const float4*)&wl[k * 16 + o];   // wave-uniform broadcast read
      a0 += v * wv4.x;
      a1 += v * wv4.y;
      a2 += v * wv4.z;
      a3 += v * wv4.w;
    }
    int n = n0 + node;
    if (n < N){
      if (o < 8){
        s[n * 8 + o + 0] = a0; s[n * 8 + o + 1] = a1;
        s[n * 8 + o + 2] = a2; s[n * 8 + o + 3] = a3;
      } else {
        int oo = o - 8;
        t[n * 8 + oo + 0] = a0; t[n * 8 + oo + 1] = a1;
        t[n * 8 + oo + 2] = a2; t[n * 8 + oo + 3] = a3;
      }
    }
    for (int i = tid; i < 4096; i += 256){
      int r = i >> 6, j = i & 63;
      int n2 = n0 + r;
      if (n2 < N)
        xb[(size_t)n2 * 64 + j] = f2bf(xs[r][2 * j]) | (f2bf(xs[r][2 * j + 1]) << 16);
    }
  }
}

// ---------------- fill3: local bsum scan + rowptr + fully atomic-free CSR scatter ------
__global__ __launch_bounds__(256) void k_fill3(const int* __restrict__ src,
                        const int* __restrict__ dst, int E,
                        const int* __restrict__ tmp, const int* __restrict__ bsumraw,
                        const int* __restrict__ erk, const int* __restrict__ sbase,
                        int* __restrict__ rowptr, int* __restrict__ esrc, int N, int nb){
  __shared__ int bs[256];
  __shared__ int ws[4];
  int tid = threadIdx.x;
  {
    int v = (tid < nb) ? bsumraw[tid] : 0;
    int lane = tid & 63, wv = tid >> 6;
    int x = v;
    #pragma unroll
    for (int off = 1; off < 64; off <<= 1){
      int y = __shfl_up(x, off, 64);
      if (lane >= off) x += y;
    }
    if (lane == 63) ws[wv] = x;
    __syncthreads();
    int p = 0;
    for (int w = 0; w < wv; ++w) p += ws[w];
    bs[tid] = x + p;
    __syncthreads();
  }
  int i = blockIdx.x * 256 + tid;
  if (i <= N){
    int r;
    if (i == 0) r = 0;
    else { int ii = i - 1, blk = ii >> 8; r = tmp[ii] + (blk ? bs[blk - 1] : 0); }
    rowptr[i] = r;
  }
  if (i < E){
    int d = dst[i];
    int ii = d - 1, blk = ii >> 8;
    int row0 = (d == 0) ? 0 : tmp[ii] + (blk ? bs[blk - 1] : 0);
    int s = (33 + (i >> 8)) & 7;                 // same shard id hist used
    esrc[row0 + sbase[(size_t)s * N + d] + erk[i]] = src[i];
  }
}

// ---------------- fused aggregation + MFMA projection (R8-proven body; 32-bit gathers) --
__global__ __launch_bounds__(512, 8) void k_agg_gemm(
    const unsigned int* __restrict__ xb,   // [N][64] uint = [N][128] bf16
    const float* __restrict__ s, const float* __restrict__ t,
    const int* __restrict__ rowptr, const int* __restrict__ esrc,
    const bf16x8* __restrict__ packh,
    const float* __restrict__ b1, const float* __restrict__ W2,
    float* __restrict__ xh2, int N)
{
  __shared__ unsigned int ylds[8192];      // 16 nodes x 1024 bf16 = 32 KB
  __shared__ float lal[8][128];
  __shared__ float red[8][16];
  int tid = threadIdx.x;
  int w = tid >> 6, lane = tid & 63;
  int m0 = blockIdx.x * 16;
  int h = lane & 7;
  int es = lane >> 3;

  // ---------------- phase 1: aggregation (2 nodes per wave) ----------------
  for (int ni = 0; ni < 2; ++ni){
    int nl = w * 2 + ni;                   // local node 0..15
    int n = m0 + nl;
    float acc[16];
    #pragma unroll
    for (int i = 0; i < 16; ++i) acc[i] = 0.f;

    if (n < N){
      int row0 = rowptr[n], deg = rowptr[n + 1] - row0;
      float tn = t[(unsigned)(n * 8 + h)];
      float sn = s[(unsigned)(n * 8 + h)];
      float selfe = __expf(leaky(sn + tn));

      // self message (un-normalized)
      {
        unsigned int v = xb[(unsigned)(n * 64 + lane)];
        float f0 = __uint_as_float(v << 16);
        float f1 = __uint_as_float(v & 0xffff0000u);
        #pragma unroll
        for (int hh = 0; hh < 8; ++hh){
          float a = __shfl(selfe, hh, 64);
          acc[2 * hh]     += a * f0;
          acc[2 * hh + 1] += a * f1;
        }
      }
      float dsum = (lane < 8) ? selfe : 0.f;

      float* lb = lal[w];
      for (int base = 0; base < deg; base += 8){
        float* la = lb + ((base >> 3) & 1) * 64;   // double-buffer
        int e = base + es;
        int cnt = min(8, deg - base);
        int srcl = 0;
        if (e < deg) srcl = esrc[row0 + e];
        float sv = s[(unsigned)(srcl * 8 + h)];    // gather (srcl=0 safe for OOB)
        // broadcast src ids, issue all 8 x-gathers up-front (MLP=8)
        int sj[8];
        #pragma unroll
        for (int j = 0; j < 8; ++j) sj[j] = __shfl(srcl, j << 3, 64);
        unsigned int vv[8];
        #pragma unroll
        for (int j = 0; j < 8; ++j) vv[j] = xb[(unsigned)(sj[j] * 64 + lane)];
        float ev = (e < deg) ? __expf(leaky(sv + tn)) : 0.f;
        dsum += ev;
        la[lane] = ev;
        #pragma unroll
        for (int j = 0; j < 8; ++j){
          if (j < cnt){
            float4 q0 = *(float4*)&la[j * 8];
            float4 q1 = *(float4*)&la[j * 8 + 4];
            float f0 = __uint_as_float(vv[j] << 16);
            float f1 = __uint_as_float(vv[j] & 0xffff0000u);
            acc[0]  += q0.x * f0; acc[1]  += q0.x * f1;
            acc[2]  += q0.y * f0; acc[3]  += q0.y * f1;
            acc[4]  += q0.z * f0; acc[5]  += q0.z * f1;
            acc[6]  += q0.w * f0; acc[7]  += q0.w * f1;
            acc[8]  += q1.x * f0; acc[9]  += q1.x * f1;
            acc[10] += q1.y * f0; acc[11] += q1.y * f1;
            acc[12] += q1.z * f0; acc[13] += q1.z * f1;
            acc[14] += q1.w * f0; acc[15] += q1.w * f1;
          }
        }
      }

      // finalize: per-head denominators, normalize
      dsum += __shfl_xor(dsum, 8, 64);
      dsum += __shfl_xor(dsum, 16, 64);
      dsum += __shfl_xor(dsum, 32, 64);
      float iden = 1.f / dsum;
      #pragma unroll
      for (int hh = 0; hh < 8; ++hh){
        float a = __shfl(iden, hh, 64);
        acc[2 * hh]     *= a;
        acc[2 * hh + 1] *= a;
      }
    }

    // write y tile to LDS (swizzled); zeros for n >= N
    #pragma unroll
    for (int hh = 0; hh < 8; ++hh){
      unsigned int p = f2bf(acc[2 * hh]) | (f2bf(acc[2 * hh + 1]) << 16);
      unsigned int byte = (unsigned)(nl * 2048 + hh * 256 + lane * 4);
      byte ^= (unsigned)((nl & 7) << 4);
      ylds[byte >> 2] = p;
    }
  }
  __syncthreads();

  // ---------------- phase 2: MFMA projection (head = wave id) + fused epilogue ----------
  int lr = lane & 15, lg = lane >> 4;
  int hD = w;
  float pnode[4] = {0.f, 0.f, 0.f, 0.f};
  bf16x8 A[4];
  #pragma unroll
  for (int kt = 0; kt < 4; ++kt){
    unsigned int byte = (unsigned)(lr * 2048 + hD * 256 + kt * 64 + lg * 16);
    byte ^= (unsigned)((lr & 7) << 4);
    A[kt] = *(const bf16x8*)((const char*)ylds + byte);
  }
  #pragma unroll
  for (int ctl = 0; ctl < 4; ++ctl){
    f32x4 acc2 = {0.f, 0.f, 0.f, 0.f};
    int pb = ((hD * 4 + ctl) * 4) * 64 + lane;
    #pragma unroll
    for (int kt = 0; kt < 4; ++kt)
      acc2 = __builtin_amdgcn_mfma_f32_16x16x32_bf16(A[kt], packh[pb + kt * 64], acc2, 0, 0, 0);
    int gc = hD * 64 + ctl * 16 + lr;
    float bb = b1[gc], wvv = W2[gc];
    #pragma unroll
    for (int r = 0; r < 4; ++r){
      float o = acc2[r] + bb; o = o > 0.f ? o : 0.f;
      pnode[r] += o * wvv;                 // node = m0 + lg*4 + r
    }
  }
  #pragma unroll
  for (int r = 0; r < 4; ++r){
    float v = pnode[r];
    v += __shfl_xor(v, 1, 64);
    v += __shfl_xor(v, 2, 64);
    v += __shfl_xor(v, 4, 64);
    v += __shfl_xor(v, 8, 64);
    pnode[r] = v;
  }
  if (lr == 0){
    #pragma unroll
    for (int r = 0; r < 4; ++r) red[w][lg * 4 + r] = pnode[r];
  }
  __syncthreads();
  if (tid < 16){
    int node = m0 + tid;
    if (node < N){
      float sum = 0.f;
      #pragma unroll
      for (int ww = 0; ww < 8; ++ww) sum += red[ww][tid];
      xh2[node] = sum;
    }
  }
}

// ---------------- agg2: scalar GAT layer (H=1,C=1), 8 lanes per node --------------------
__global__ __launch_bounds__(256) void k_agg2(const float* __restrict__ xh2,
                       const int* __restrict__ rowptr, const int* __restrict__ esrc,
                       const float* __restrict__ as2p, const float* __restrict__ ad2p,
                       const float* __restrict__ b2p,
                       float* __restrict__ out, int N)
{
  int g = blockIdx.x * 32 + (threadIdx.x >> 3);
  int li = threadIdx.x & 7;
  if (g >= N) return;
  float a_s = as2p[0], a_d = ad2p[0], b2 = b2p[0];
  float xn = xh2[g];
  float t2 = a_d * xn;
  float den = 0.f, num = 0.f;
  if (li == 0){
    float w0 = __expf(leaky(a_s * xn + t2));   // self loop
    den = w0; num = w0 * xn;
  }
  int row1 = rowptr[g + 1];
  for (int e = rowptr[g] + li; e < row1; e += 8){
    int src = esrc[e];
    float xs2 = xh2[src];
    float w = __expf(leaky(a_s * xs2 + t2));
    den += w; num += w * xs2;
  }
  den += __shfl_xor(den, 1, 64); num += __shfl_xor(num, 1, 64);
  den += __shfl_xor(den, 2, 64); num += __shfl_xor(num, 2, 64);
  den += __shfl_xor(den, 4, 64); num += __shfl_xor(num, 4, 64);
  if (li == 0) out[g] = num / den + b2;
}

extern "C" void kernel_launch(void* const* d_in, const int* in_sizes, int n_in,
                              void* d_out, int out_size, void* d_ws, size_t ws_size,
                              hipStream_t stream) {
  const float* x   = (const float*)d_in[0];
  const int*   ei  = (const int*)d_in[1];
  const float* W1  = (const float*)d_in[2];
  const float* as1 = (const float*)d_in[3];
  const float* ad1 = (const float*)d_in[4];
  const float* b1  = (const float*)d_in[5];
  const float* W2  = (const float*)d_in[6];
  const float* as2 = (const float*)d_in[7];
  const float* ad2 = (const float*)d_in[8];
  const float* b2  = (const float*)d_in[9];
  float* out = (float*)d_out;

  int N = in_sizes[0] / 128;
  int E = in_sizes[1] / 2;
  const int* src_in = ei;
  const int* dst_in = ei + E;

  char* w = (char*)d_ws;
  auto alloc = [&](size_t bytes){ void* p = (void*)w; w += (bytes + 255) & ~(size_t)255; return p; };
  unsigned int* xb   = (unsigned int*)alloc((size_t)N * 64 * 4);    // 12.8 MB
  float* s      = (float*)alloc((size_t)N * 8 * 4);
  float* t      = (float*)alloc((size_t)N * 8 * 4);
  float* xh2    = (float*)alloc((size_t)N * 4);
  int*   deg8   = (int*)alloc((size_t)8 * N * 4);                   // sharded counters
  int*   sbase  = (int*)alloc((size_t)8 * N * 4);
  int*   rowptr = (int*)alloc((size_t)(N + 1) * 4);
  int*   esrc   = (int*)alloc((size_t)E * 4);
  int*   erk    = (int*)alloc((size_t)E * 4);
  int*   tmp    = (int*)alloc((size_t)N * 4);
  int*   bsum   = (int*)alloc((size_t)1024 * 4);
  float* wst    = (float*)alloc((size_t)2048 * 4);
  bf16x8* packh = (bf16x8*)alloc((size_t)8192 * 16);

  int nb     = (N + 255) / 256;
  int nhist  = (E + 255) / 256;
  int ntiles = (N + 63) / 64;

  hipMemsetAsync(deg8, 0, (size_t)8 * N * 4, stream);
  k_prep0<<<33 + nhist, 256, 0, stream>>>(W1, as1, ad1, wst, packh, dst_in, deg8, erk, N, E);
  k_scanlog<<<nb + ntiles, 256, 0, stream>>>(deg8, sbase, tmp, bsum, x, wst, s, t, xb, N, nb);
  k_fill3<<<(E + 255) / 256, 256, 0, stream>>>(src_in, dst_in, E, tmp, bsum, erk, sbase,
                                               rowptr, esrc, N, nb);
  k_agg_gemm<<<(N + 15) / 16, 512, 0, stream>>>(xb, s, t, rowptr, esrc, packh, b1, W2, xh2, N);
  k_agg2<<<(N + 31) / 32, 256, 0, stream>>>(xh2, rowptr, esrc, as2, ad2, b2, out, N);
}